// Round 8
// baseline (5991.773 us; speedup 1.0000x reference)
//
#include <hip/hip_runtime.h>
#include <stdint.h>
#include <math.h>

// Problem dims (fixed by reference setup_inputs)
#define NN 8
#define TT 256
#define BB 4
#define DD 512
#define VV 32000
#define MM (NN*TT*BB)          // 8192 rows

// MFMA GEMM tiling (gemm3 full-path / fallback)
#define TM 128
#define TN 128
#define VT 5                   // n-tiles swept per block (fallback only now)
#define GX (VV/(TN*VT))        // 50
#define CHUNKS3 32             // 3-pass kernel: K=16 per chunk (2048 halves)

// gemm1 (pass-1) tiling: 256x256 tile, 8 waves, BK=32 ring-2, 2 blocks/CU
#define BT 256
#define NWB (VV/BT)            // 125 W-blocks of 256 cols

#define RCAP 2048              // max flagged rows
#define PCAP 16384             // max (row, W-block) rescore pairs
#define MARGIN 3.0e5f          // scaled-units confidence margin (~15 sigma)

typedef _Float16 half8  __attribute__((ext_vector_type(8)));
typedef float    f32x4  __attribute__((ext_vector_type(4)));
typedef float    f32x16 __attribute__((ext_vector_type(16)));
typedef unsigned long long u64;

#define MFMA32(a,b,c) __builtin_amdgcn_mfma_f32_32x32x16_f16((a),(b),(c),0,0,0)
#define MFMA16(a,b,c) __builtin_amdgcn_mfma_f32_16x16x32_f16((a),(b),(c),0,0,0)

// ---- workspace layout ----
#define OFF_P1     0ull              // 64KB u64[8192]
#define OFF_P2     65536ull          // 64KB
#define OFF_PE     131072ull         // 64KB
#define OFF_FLAG   196608ull         // 32KB int[8192]
#define OFF_LIST   229376ull         // 8KB  (unused, kept for layout stability)
#define OFF_CNT    237568ull         // 4KB region: cnt @ +0, cnt2 @ +4
#define OFF_SCORES 241664ull         // 32KB
#define OFF_AH     294912ull
#define AH_SZ      8388608ull        // 8192*512*2 B
#define OFF_AL     (OFF_AH + AH_SZ)
#define OFF_WH     (OFF_AL + AH_SZ)
#define WH_SZ      32768000ull       // 32000*512*2 B
#define OFF_WL     (OFF_WH + WH_SZ)
// candidate-pruning region
#define OFF_BMAX   (OFF_WL + WH_SZ)          // u32[125][8192] = 4,096,000 B
#define OFF_PAIRS  (OFF_BMAX + 4096000ull)   // u32[PCAP] = 65,536 B
#define WS_NEED2   (OFF_BMAX + 4194304ull)   // ~86.8 MB : full fast path
#define WS_NEED1   (OFF_WL + WH_SZ)          // ~82.6 MB : 3-pass-everywhere path

// ---------- helpers ----------

__device__ __forceinline__ uint32_t fkey(float v){
  uint32_t b = __float_as_uint(v);
  return b ^ ((b & 0x80000000u) ? 0xFFFFFFFFu : 0x80000000u);
}
__device__ __forceinline__ float unfkey(uint32_t k){
  uint32_t b = (k & 0x80000000u) ? (k ^ 0x80000000u) : ~k;
  return __uint_as_float(b);
}

__device__ __forceinline__ uint32_t rotl32(uint32_t x, int r){
  return (x << r) | (x >> (32 - r));
}
__device__ __forceinline__ void threefry2x32(uint32_t k0, uint32_t k1,
                                             uint32_t& x0, uint32_t& x1){
  const uint32_t ks0 = k0, ks1 = k1, ks2 = k0 ^ k1 ^ 0x1BD11BDAu;
  x0 += ks0; x1 += ks1;
  x0 += x1; x1 = rotl32(x1,13); x1 ^= x0;
  x0 += x1; x1 = rotl32(x1,15); x1 ^= x0;
  x0 += x1; x1 = rotl32(x1,26); x1 ^= x0;
  x0 += x1; x1 = rotl32(x1, 6); x1 ^= x0;
  x0 += ks1; x1 += ks2 + 1u;
  x0 += x1; x1 = rotl32(x1,17); x1 ^= x0;
  x0 += x1; x1 = rotl32(x1,29); x1 ^= x0;
  x0 += x1; x1 = rotl32(x1,16); x1 ^= x0;
  x0 += x1; x1 = rotl32(x1,24); x1 ^= x0;
  x0 += ks2; x1 += ks0 + 2u;
  x0 += x1; x1 = rotl32(x1,13); x1 ^= x0;
  x0 += x1; x1 = rotl32(x1,15); x1 ^= x0;
  x0 += x1; x1 = rotl32(x1,26); x1 ^= x0;
  x0 += x1; x1 = rotl32(x1, 6); x1 ^= x0;
  x0 += ks0; x1 += ks1 + 3u;
  x0 += x1; x1 = rotl32(x1,17); x1 ^= x0;
  x0 += x1; x1 = rotl32(x1,29); x1 ^= x0;
  x0 += x1; x1 = rotl32(x1,16); x1 ^= x0;
  x0 += x1; x1 = rotl32(x1,24); x1 ^= x0;
  x0 += ks1; x1 += ks2 + 4u;
  x0 += x1; x1 = rotl32(x1,13); x1 ^= x0;
  x0 += x1; x1 = rotl32(x1,15); x1 ^= x0;
  x0 += x1; x1 = rotl32(x1,26); x1 ^= x0;
  x0 += x1; x1 = rotl32(x1, 6); x1 ^= x0;
  x0 += ks2; x1 += ks0 + 5u;
}

__device__ __forceinline__ float uniform_from_bits(uint32_t bits){
  return __uint_as_float((bits >> 9) | 0x3f800000u) - 1.0f;
}

// async 16B global -> LDS (global addr per-lane, LDS dest wave-uniform + lane*16)
__device__ __forceinline__ void gload16(const _Float16* g, _Float16* l){
  __builtin_amdgcn_global_load_lds(
      (const __attribute__((address_space(1))) uint32_t*)g,
      (__attribute__((address_space(3))) uint32_t*)l, 16, 0, 0);
}

// ---------- kernel: init all header accumulators ----------
__global__ void init_kernel(u64* p1, u64* p2, u64* pE, int* flag,
                            unsigned int* cnt, unsigned int* cnt2){
  int i = blockIdx.x * blockDim.x + threadIdx.x;
  if (i < MM){ p1[i] = 0ULL; p2[i] = 0ULL; pE[i] = 0ULL; flag[i] = 0; }
  if (i == 0){ *cnt = 0u; *cnt2 = 0u; }
}

// ---------- conversion: fp32 [rows,512] -> split-f16 planes, tile layout ------
// hi = f16(x*scale), lo = f16(x*scale - hi) [natural residual].
// Plane chunk c = rt*8192 + kc*128 + rin (kc=k/8 in 0..63), 8 halves each.
__global__ __launch_bounds__(256)
void convert_kernel(const float* __restrict__ src,
                    _Float16* __restrict__ hi, _Float16* __restrict__ lo,
                    float scale){
  const int k0 = blockIdx.x & 15;       // 32-k slab
  const int rt = blockIdx.x >> 4;
  __shared__ _Float16 hbuf[4096], lbuf[4096];
  const int t = threadIdx.x;
  #pragma unroll
  for (int i = 0; i < 4; ++i){
    const int f = i * 256 + t;
    const int rin = f >> 3, c4 = f & 7;
    const float4 v4 = *(const float4*)&src[(size_t)(rt*128+rin)*DD + k0*32 + c4*4];
    const int base = (c4 >> 1) * 1024 + rin * 8 + (c4 & 1) * 4;
    float vv[4] = {v4.x, v4.y, v4.z, v4.w};
    #pragma unroll
    for (int j = 0; j < 4; ++j){
      const float s = vv[j] * scale;
      const _Float16 hh = (_Float16)s;
      hbuf[base + j] = hh;
      lbuf[base + j] = (_Float16)(s - (float)hh);
    }
  }
  __syncthreads();
  const size_t ob = ((size_t)rt * 8192 + (size_t)k0 * 512) * 8;
  #pragma unroll
  for (int i = 0; i < 2; ++i){
    const int cl = i * 256 + t;
    *(half8*)&hi[ob + (size_t)cl * 8] = *(const half8*)&hbuf[cl * 8];
    *(half8*)&lo[ob + (size_t)cl * 8] = *(const half8*)&lbuf[cl * 8];
  }
}

// ---------- kernel A: pass-1 hi*hi GEMM, 256x256 tile, RING-2, 2 blocks/CU ----
// R8: keep the read-optimal 256^2 8-wave geometry (0.75 ds_read/MFMA) but cut
// LDS 130->68 KB (ring-2, prefetch depth 1) so 2 blocks co-reside per CU.
// One block's LDS-read burst overlaps the partner's MFMA burst -- the lever
// that fixed gemm3s (R2->R3). Schedule shape (vmcnt(0)+barrier per slab with
// 1-deep prefetch) is the race-verified gemm3s/R6 pattern.
// Counted-lgkm two-cluster pipeline within each slab (R5).
__global__ __launch_bounds__(512, 4)
void gemm1_kernel(const _Float16* __restrict__ Ahp, const _Float16* __restrict__ Whp,
                  u64* __restrict__ p1, u64* __restrict__ p2,
                  uint32_t* __restrict__ bmax){
  __shared__ __align__(16) _Float16 sR[2][8192];   // 32 KB: ring-2 R K-slabs
  __shared__ __align__(16) _Float16 sW[2][8192];   // 32 KB: ring-2 W K-slabs
  __shared__ u64 lmax1[BT];
  __shared__ uint32_t lmax2[BT];

  const int tid = threadIdx.x, wid = tid >> 6, lane = tid & 63;
  const int l31 = lane & 31, lhi = lane >> 5;
  const int wm = wid >> 2;          // 0..1 : which 128-row half of the R tile
  const int wn = wid & 3;           // 0..3 : which 64-col strip of the W tile
  const int by = blockIdx.x;        // R tile (32)
  const int bx = blockIdx.y;        // W tile (125)

  if (tid < BT){ lmax1[tid] = 0ULL; lmax2[tid] = 0u; }

  // staging geometry: 16 chunks of 512 halves per slot plane; wave stages 2 R + 2 W
  const int cc = wid * 2;                 // chunk pair base
  const int h  = cc >> 3;                 // which 128-row half-plane
  const size_t gsoff = (size_t)h * 65536 + (size_t)(cc & 7) * 512 + (size_t)lane * 8;
  const _Float16* grs = Ahp + (size_t)(by * 2) * 65536 + gsoff;
  const _Float16* gws = Whp + (size_t)(bx * 2) * 65536 + gsoff;
  const int lsoff = cc * 512;

  #define STAGE1(t) do { \
    const size_t ko_ = (size_t)(t) * 4096; \
    _Float16* lr_ = &sR[(t) & 1][lsoff]; \
    _Float16* lw_ = &sW[(t) & 1][lsoff]; \
    gload16(grs + ko_,       lr_); \
    gload16(grs + ko_ + 512, lr_ + 512); \
    gload16(gws + ko_,       lw_); \
    gload16(gws + ko_ + 512, lw_ + 512); \
  } while(0)

  STAGE1(0);                          // prefetch depth 1

  f32x16 acc[2][4];
  #pragma unroll
  for (int c = 0; c < 2; ++c)
    #pragma unroll
    for (int m = 0; m < 4; ++m) acc[c][m] = (f32x16)0.0f;

  // fragment base offsets (in halves) within a slot: [half][kc 4][row 128][8]
  const int wbase = (wn >> 1) * 4096 + (wn & 1) * 512;  // + kc*1024 + c*256 + l31*8
  const int rbase = wm * 4096;                          // + kc*1024 + m*256 + l31*8

  for (int t = 0; t < 16; ++t){
    // own slab-t stage loads complete; all waves' writes to slot t&1 done
    asm volatile("s_waitcnt vmcnt(0)" ::: "memory");
    __builtin_amdgcn_s_barrier();           // slab t fully in LDS (all waves)

    const _Float16* sRs = &sR[t & 1][0];
    const _Float16* sWs = &sW[t & 1][0];

    // ---- issue sub0 reads (kc = lhi): 6x ds_read_b128 ----
    half8 wf0[2], rf0[4];
    {
      const int kco = lhi * 1024;
      #pragma unroll
      for (int c = 0; c < 2; ++c)
        wf0[c] = *(const half8*)&sWs[wbase + kco + c * 256 + l31 * 8];
      #pragma unroll
      for (int m = 0; m < 4; ++m)
        rf0[m] = *(const half8*)&sRs[rbase + kco + m * 256 + l31 * 8];
    }
    __builtin_amdgcn_sched_barrier(0);      // sub0 reads issued before anything below

    // ---- issue sub1 reads (kc = 2+lhi) + next-slab stage (vmem) ----
    half8 wf1[2], rf1[4];
    {
      const int kco = (2 + lhi) * 1024;
      #pragma unroll
      for (int c = 0; c < 2; ++c)
        wf1[c] = *(const half8*)&sWs[wbase + kco + c * 256 + l31 * 8];
      #pragma unroll
      for (int m = 0; m < 4; ++m)
        rf1[m] = *(const half8*)&sRs[rbase + kco + m * 256 + l31 * 8];
    }
    if (t < 15) STAGE1(t + 1);  // writes slot (t+1)&1: its readers (slab t-1)
                                // finished lgkm(0) before the barrier above

    // ---- cluster 0: wait sub0 only (sub1 + stage still in flight) ----
    asm volatile("s_waitcnt lgkmcnt(6)" ::: "memory");
    __builtin_amdgcn_sched_barrier(0);
    __builtin_amdgcn_s_setprio(1);
    #pragma unroll
    for (int c = 0; c < 2; ++c)
      #pragma unroll
      for (int m = 0; m < 4; ++m)
        acc[c][m] = MFMA32(wf0[c], rf0[m], acc[c][m]);
    __builtin_amdgcn_s_setprio(0);

    // ---- cluster 1: sub1 reads have been hiding under cluster 0 ----
    asm volatile("s_waitcnt lgkmcnt(0)" ::: "memory");
    __builtin_amdgcn_sched_barrier(0);
    __builtin_amdgcn_s_setprio(1);
    #pragma unroll
    for (int c = 0; c < 2; ++c)
      #pragma unroll
      for (int m = 0; m < 4; ++m)
        acc[c][m] = MFMA32(wf1[c], rf1[m], acc[c][m]);
    __builtin_amdgcn_s_setprio(0);
  }

  // ---- epilogue: per-lane running top-2 (rows are lane-local: D col = l31) ----
  // D row (v,lhi) -> W col = bx*256 + wn*64 + c*32 + (v&3)+8*(v>>2)+4*lhi
  // D col (l31)   -> R row = by*256 + wm*128 + m*32 + l31
  const int colbase = bx * BT + wn * 64;
  #pragma unroll
  for (int m = 0; m < 4; ++m){
    float t1 = -3.4e38f, t2 = -3.4e38f;
    uint32_t c1 = 0;
    #pragma unroll
    for (int c = 0; c < 2; ++c){
      #pragma unroll
      for (int v = 0; v < 16; ++v){
        const float val = acc[c][m][v];
        const uint32_t col = (uint32_t)(colbase + c * 32 + (v & 3) + 8 * (v >> 2) + 4 * lhi);
        const bool gt = val > t1;               // strict: earliest col wins ties
        t2 = gt ? t1 : fmaxf(t2, val);
        c1 = gt ? col : c1;
        t1 = fmaxf(t1, val);
      }
    }
    const u64 pk = ((u64)fkey(t1) << 32) | (u64)(~c1);
    const uint32_t k2 = fkey(t2);
    // merge the lane pair (lhi halves see disjoint cols of the same row)
    const u64 opk = __shfl_xor(pk, 32, 64);
    const uint32_t ok2 = __shfl_xor(k2, 32, 64);
    const u64 hi2 = pk > opk ? pk : opk;
    const uint32_t lo1 = (uint32_t)((pk > opk ? opk : pk) >> 32);
    uint32_t sec = k2 > ok2 ? k2 : ok2;
    sec = sec > lo1 ? sec : lo1;
    if (lhi == 0){
      const int row = wm * 128 + m * 32 + l31;
      const u64 old = atomicMax(&lmax1[row], hi2);
      const u64 losr = old < hi2 ? old : hi2;
      const uint32_t lk = (uint32_t)(losr >> 32);
      atomicMax(&lmax2[row], sec > lk ? sec : lk);
    }
  }

  __syncthreads();
  if (tid < BT){
    const int g = by * BT + tid;
    const u64 l1 = lmax1[tid];
    const u64 l2 = ((u64)lmax2[tid]) << 32;
    const u64 old = atomicMax(&p1[g], l1);
    const u64 losr = old < l1 ? old : l1;
    atomicMax(&p2[g], losr);
    atomicMax(&p2[g], l2);
    // per-(row, W-block) approx top-1 key; exclusive writer, coalesced
    bmax[(size_t)bx * MM + g] = (uint32_t)(l1 >> 32);
  }
  #undef STAGE1
}

// ---------- kernel: resolve borderline rows + emit (row, W-block) pairs ------
// Merged resolve+cand (one launch). Wave per row: gap test, flag write, then
// candidate-block scan: argmax of a flagged row lies in a block whose approx
// top-1 >= p1 - MARGIN (same error-bound logic as the gap test).
__global__ __launch_bounds__(256)
void resolve_cand_kernel(const u64* __restrict__ p1, const u64* __restrict__ p2,
                         int* __restrict__ flag,
                         const uint32_t* __restrict__ bmax,
                         uint32_t* __restrict__ pairs,
                         unsigned int* __restrict__ cnt2){
  const int wid = threadIdx.x >> 6, lane = threadIdx.x & 63;
  const int r = blockIdx.x * 4 + wid;
  const float f1 = unfkey((uint32_t)(p1[r] >> 32));
  const float f2 = unfkey((uint32_t)(p2[r] >> 32));
  if (f1 - f2 > MARGIN) return;
  if (lane == 0) flag[r] = 1;
  const float thr = f1 - MARGIN;
  #pragma unroll
  for (int s = 0; s < 2; ++s){
    const int b = lane + s * 64;
    if (b < NWB){
      const float f = unfkey(bmax[(size_t)b * MM + r]);
      if (f >= thr){
        const unsigned int i = atomicAdd(cnt2, 1u);
        if (i < PCAP) pairs[i] = ((uint32_t)r << 7) | (uint32_t)b;
      }
    }
  }
}

// ---------- kernel: exact fp32 rescore of candidate (row, block) pairs -------
// 256 threads per pair: thread t scores col b*256+t as sum_k (ah+al)(wh+wl)
// in fp32 (strictly more accurate than the old 3-pass MFMA rescore).
__global__ __launch_bounds__(256)
void rescx_kernel(const _Float16* __restrict__ Ahp, const _Float16* __restrict__ Alp,
                  const _Float16* __restrict__ Whp, const _Float16* __restrict__ Wlp,
                  const uint32_t* __restrict__ pairs,
                  const unsigned int* __restrict__ cnt2p,
                  u64* __restrict__ pE){
  __shared__ float as[DD];
  __shared__ u64 red;
  const unsigned int c2 = *cnt2p;
  const unsigned int n = c2 < (unsigned int)PCAP ? c2 : (unsigned int)PCAP;
  const int tid = threadIdx.x;

  for (unsigned int i = blockIdx.x; i < n; i += gridDim.x){
    const uint32_t pr = pairs[i];
    const int r = (int)(pr >> 7), b = (int)(pr & 127u);

    if (tid < 64){          // stage exact scaled A row: as[k] = ah + al
      const size_t base = ((size_t)(r >> 7) * 8192 + (size_t)tid * 128 + (r & 127)) * 8;
      const half8 h = *(const half8*)&Ahp[base];
      const half8 l = *(const half8*)&Alp[base];
      #pragma unroll
      for (int j = 0; j < 8; ++j) as[tid * 8 + j] = (float)h[j] + (float)l[j];
    }
    if (tid == 0) red = 0ULL;
    __syncthreads();

    const int v = b * 256 + tid;
    const size_t wb = ((size_t)(v >> 7) * 8192 + (size_t)(v & 127)) * 8;
    float s = 0.0f;
    for (int kc = 0; kc < 64; ++kc){
      const half8 wh = *(const half8*)&Whp[wb + (size_t)kc * 1024];
      const half8 wl = *(const half8*)&Wlp[wb + (size_t)kc * 1024];
      #pragma unroll
      for (int j = 0; j < 8; ++j)
        s = fmaf(as[kc * 8 + j], (float)wh[j] + (float)wl[j], s);
    }
    const u64 key = ((u64)fkey(s) << 32) | (u64)(~(uint32_t)v);
    atomicMax(&red, key);                    // LDS reduce
    __syncthreads();
    if (tid == 0) atomicMax(&pE[r], red);
    __syncthreads();
  }
}

// ---------- kernel B: 3-pass split-f16 GEMM + argmax (full-vocab path) -------
__global__ __launch_bounds__(256, 4)
void gemm3_kernel(const _Float16* __restrict__ Ahp, const _Float16* __restrict__ Alp,
                  const _Float16* __restrict__ Whp, const _Float16* __restrict__ Wlp,
                  u64* __restrict__ out,
                  const int* __restrict__ rowlist,
                  const unsigned int* __restrict__ cntp){
  if (cntp && (unsigned int)(blockIdx.x * TM) >= *cntp) return;

  __shared__ __align__(16) _Float16 sAh[2][2048], sAl[2][2048], sBh[2][2048], sBl[2][2048];
  __shared__ u64 lmax[TM];

  const int tid = threadIdx.x, wid = tid >> 6, lane = tid & 63;
  const int l31 = lane & 31, lhi = lane >> 5;
  const int wave_m = (wid & 1) * 64, wave_n = (wid >> 1) * 64;
  const int by = blockIdx.x;
  const int nt = blockIdx.y;

  if (tid < TM) lmax[tid] = 0ULL;

  _Float16* stg0 = (wid == 0) ? sAh[0] : (wid == 1) ? sAl[0] : (wid == 2) ? sBh[0] : sBl[0];
  _Float16* stg1 = (wid == 0) ? sAh[1] : (wid == 1) ? sAl[1] : (wid == 2) ? sBh[1] : sBl[1];

  f32x16 acc[2][2];
  #pragma unroll
  for (int i = 0; i < 2; ++i)
    #pragma unroll
    for (int j = 0; j < 2; ++j) acc[i][j] = (f32x16)0.0f;

  const _Float16* gbase =
      (wid == 0) ? Ahp + (size_t)by * 65536 : (wid == 1) ? Alp + (size_t)by * 65536
    : (wid == 2) ? Whp + (size_t)nt * 65536 :              Wlp + (size_t)nt * 65536;

  {
    const _Float16* g = gbase + lane * 8;
    #pragma unroll
    for (int j = 0; j < 4; ++j) gload16(g + j * 512, stg0 + j * 512);
  }

  for (int kk = 0; kk < CHUNKS3; ++kk){
    __syncthreads();
    if (kk < CHUNKS3 - 1){
      const _Float16* g = gbase + (size_t)(kk + 1) * 2048 + lane * 8;
      _Float16* s = (kk & 1) ? stg0 : stg1;
      #pragma unroll
      for (int j = 0; j < 4; ++j) gload16(g + j * 512, s + j * 512);
    }
    const int cb = kk & 1;

    half8 fah[2], fal[2], fbh[2], fbl[2];
    #pragma unroll
    for (int t = 0; t < 2; ++t){
      const int ra = lhi * 128 + wave_m + t * 32 + l31;
      const int rb = lhi * 128 + wave_n + t * 32 + l31;
      fah[t] = *(const half8*)&sAh[cb][ra * 8];
      fal[t] = *(const half8*)&sAl[cb][ra * 8];
      fbh[t] = *(const half8*)&sBh[cb][rb * 8];
      fbl[t] = *(const half8*)&sBl[cb][rb * 8];
    }
    #pragma unroll
    for (int ti = 0; ti < 2; ++ti)
      #pragma unroll
      for (int tj = 0; tj < 2; ++tj){
        acc[ti][tj] = MFMA32(fah[ti], fbh[tj], acc[ti][tj]);
        acc[ti][tj] = MFMA32(fah[ti], fbl[tj], acc[ti][tj]);
        acc[ti][tj] = MFMA32(fal[ti], fbh[tj], acc[ti][tj]);
      }
  }

  const int ncol0 = nt * TN + wave_n;
  #pragma unroll
  for (int ti = 0; ti < 2; ++ti){
    #pragma unroll
    for (int v = 0; v < 16; ++v){
      const int mloc = wave_m + ti * 32 + (v & 3) + 8 * (v >> 2) + 4 * lhi;
      u64 best = 0ULL;
      #pragma unroll
      for (int tj = 0; tj < 2; ++tj){
        const int col = ncol0 + tj * 32 + l31;
        const u64 p = ((u64)fkey(acc[ti][tj][v]) << 32) | (u64)(~(uint32_t)col);
        if (p > best) best = p;
      }
      #pragma unroll
      for (int m = 16; m > 0; m >>= 1){
        const u64 o = __shfl_xor(best, m, 64);
        if (o > best) best = o;
      }
      if (l31 == 0) atomicMax(&lmax[mloc], best);
    }
  }

  __syncthreads();
  if (tid < TM){
    int g;
    if (rowlist){
      const int i = by * TM + tid;
      const unsigned int c = *cntp;
      g = ((unsigned int)i < c) ? rowlist[i] : rowlist[0];
    } else {
      g = by * TM + tid;
    }
    atomicMax(&out[g], lmax[tid]);
  }
}

// ---------- fallback (round-3 verified): in-loop-convert GEMM ----------
__device__ __forceinline__ void cvt8(const float4& p, const float4& q, float scale,
                                     half8& h, half8& l){
  float v[8] = {p.x,p.y,p.z,p.w,q.x,q.y,q.z,q.w};
  #pragma unroll
  for (int j = 0; j < 8; ++j){
    const float s = v[j] * scale;
    const _Float16 hh = (_Float16)s;
    h[j] = hh;
    l[j] = (_Float16)((s - (float)hh) * 4096.0f);
  }
}

#define FBK 32
__global__ __launch_bounds__(256, 2)
void gemm_fallback_kernel(const float* __restrict__ A,
                          const float* __restrict__ W,
                          u64* __restrict__ packed){
  __shared__ __align__(16) _Float16 Ah[TM][40];
  __shared__ __align__(16) _Float16 Al[TM][40];
  __shared__ __align__(16) _Float16 Bh[TN][40];
  __shared__ __align__(16) _Float16 Bl[TN][40];
  __shared__ u64 lmax[TM];

  const int tid   = threadIdx.x;
  const int mtile = blockIdx.y * TM;
  const int wid    = tid >> 6;
  const int lane   = tid & 63;
  const int lm     = lane & 15;
  const int lk     = lane >> 4;
  const int wave_m = (wid & 1) * 64;
  const int wave_n = (wid >> 1) * 64;
  const int srow = tid >> 2;
  const int skc  = (tid & 3) * 8;

  if (tid < TM) lmax[tid] = 0ULL;

  for (int vt = 0; vt < VT; ++vt){
    const int ntile = (blockIdx.x * VT + vt) * TN;
    f32x4 acc1[4][4], acc2[4][4];
    #pragma unroll
    for (int i = 0; i < 4; ++i)
      #pragma unroll
      for (int j = 0; j < 4; ++j){ acc1[i][j] = (f32x4)0.0f; acc2[i][j] = (f32x4)0.0f; }

    for (int k0 = 0; k0 < DD; k0 += FBK){
      const float* pa0 = &A[(size_t)(mtile + srow     ) * DD + k0 + skc];
      const float* pa1 = &A[(size_t)(mtile + srow + 64) * DD + k0 + skc];
      const float* pb0 = &W[(size_t)(ntile + srow     ) * DD + k0 + skc];
      const float* pb1 = &W[(size_t)(ntile + srow + 64) * DD + k0 + skc];
      const float4 a00 = *(const float4*)(pa0), a01 = *(const float4*)(pa0 + 4);
      const float4 a10 = *(const float4*)(pa1), a11 = *(const float4*)(pa1 + 4);
      const float4 b00 = *(const float4*)(pb0), b01 = *(const float4*)(pb0 + 4);
      const float4 b10 = *(const float4*)(pb1), b11 = *(const float4*)(pb1 + 4);

      __syncthreads();
      half8 h, l;
      cvt8(a00, a01, 4096.0f,  h, l);
      *(half8*)&Ah[srow     ][skc] = h; *(half8*)&Al[srow     ][skc] = l;
      cvt8(a10, a11, 4096.0f,  h, l);
      *(half8*)&Ah[srow + 64][skc] = h; *(half8*)&Al[srow + 64][skc] = l;
      cvt8(b00, b01, 16384.0f, h, l);
      *(half8*)&Bh[srow     ][skc] = h; *(half8*)&Bl[srow     ][skc] = l;
      cvt8(b10, b11, 16384.0f, h, l);
      *(half8*)&Bh[srow + 64][skc] = h; *(half8*)&Bl[srow + 64][skc] = l;
      __syncthreads();

      half8 ah[4], al[4], bh[4], bl[4];
      #pragma unroll
      for (int ti = 0; ti < 4; ++ti){
        const int r = wave_m + ti * 16 + lm;
        ah[ti] = *(const half8*)&Ah[r][lk * 8];
        al[ti] = *(const half8*)&Al[r][lk * 8];
      }
      #pragma unroll
      for (int tj = 0; tj < 4; ++tj){
        const int r = wave_n + tj * 16 + lm;
        bh[tj] = *(const half8*)&Bh[r][lk * 8];
        bl[tj] = *(const half8*)&Bl[r][lk * 8];
      }
      #pragma unroll
      for (int ti = 0; ti < 4; ++ti)
        #pragma unroll
        for (int tj = 0; tj < 4; ++tj){
          acc1[ti][tj] = MFMA16(ah[ti], bh[tj], acc1[ti][tj]);
          acc2[ti][tj] = MFMA16(ah[ti], bl[tj], acc2[ti][tj]);
          acc2[ti][tj] = MFMA16(al[ti], bh[tj], acc2[ti][tj]);
        }
    }

    #pragma unroll
    for (int ti = 0; ti < 4; ++ti){
      #pragma unroll
      for (int v = 0; v < 4; ++v){
        const int mloc = wave_m + ti * 16 + lk * 4 + v;
        u64 best = 0ULL;
        #pragma unroll
        for (int tj = 0; tj < 4; ++tj){
          const int col = ntile + wave_n + tj * 16 + lm;
          const float lg = acc1[ti][tj][v] + acc2[ti][tj][v] * (1.0f/4096.0f);
          const u64 p = ((u64)fkey(lg) << 32) | (u64)(~(uint32_t)col);
          if (p > best) best = p;
        }
        atomicMax(&lmax[mloc], best);
      }
    }
  }

  __syncthreads();
  if (tid < TM) atomicMax(&packed[mtile + tid], lmax[tid]);
}

// ---------- kernel: scores[r] = sqrt(D) * dot(outputs[n,t,:], W[argmax_r]) ----
__global__ __launch_bounds__(256)
void score_kernel(const float* __restrict__ outputs,
                  const float* __restrict__ W,
                  const u64* __restrict__ p1, const u64* __restrict__ pE,
                  const int* __restrict__ flag,
                  float* __restrict__ scores){
  const int wave = threadIdx.x >> 6;
  const int lane = threadIdx.x & 63;
  const int r = blockIdx.x * 4 + wave;
  const u64 pe = pE[r];
  const u64 pk = (flag[r] && pe != 0ULL) ? pe : p1[r];
  const uint32_t idx = ~(uint32_t)pk;
  const int n = r >> 10;
  const int t = (r >> 2) & (TT - 1);
  const float* ov = outputs + ((size_t)(n * TT + t) << 9);
  const float* wv = W + (size_t)idx * DD;
  float s = 0.0f;
  #pragma unroll
  for (int j = 0; j < 8; ++j){
    const int d = lane + j * 64;
    s = fmaf(ov[d], wv[d], s);
  }
  #pragma unroll
  for (int off = 32; off > 0; off >>= 1) s += __shfl_down(s, off);
  if (lane == 0) scores[r] = s * 22.62741699796952f;  // float32(sqrt(512))
}

// ---------- kernel: sequential accept/reject scan + mask scatter ----------
__global__ __launch_bounds__(256)
void scan_kernel(const float* __restrict__ scores, float* __restrict__ mask_out){
  __shared__ float sc[MM];
  __shared__ float uu[TT * NN];

  const int tid = threadIdx.x;

  for (int i = tid; i < MM; i += 256){
    mask_out[i] = 0.0f;
    sc[i] = scores[i];
  }

  // Partitionable threefry (JAX >= 0.4.36): key' = tf2x32((0,42),(0,t));
  // element n: (o0,o1) = tf2x32(key',(0,n)); bits = o0^o1.
  {
    const int t = tid;
    uint32_t k0 = 0u, k1 = (uint32_t)t;
    threefry2x32(0u, 42u, k0, k1);
    #pragma unroll
    for (int n = 0; n < NN; ++n){
      uint32_t x0 = 0u, x1 = (uint32_t)n;
      threefry2x32(k0, k1, x0, x1);
      uu[t * NN + n] = uniform_from_bits(x0 ^ x1);
    }
  }
  __syncthreads();

  if (tid < NN){
    const int n = tid;
    int x = 0, y = 0;
    for (int t = 0; t < TT; ++t){
      const int idx0 = x * BB + y;
      mask_out[n * (TT * BB) + idx0] = 1.0f;
      const float scx0 = sc[n * (TT * BB) + idx0];
      const float scx1 = sc[n * (TT * BB) + t * BB];
      const float prob = 1.0f / (1.0f + expf(-((scx0 - scx1) / 10.0f)));
      int accept = (uu[t * NN + n] < prob) ? 1 : 0;
      if (y + accept >= BB) accept = 0;
      y = (y + accept) * accept;
      x = x * accept + (t + 1) * (1 - accept);
    }
  }
}

// ---------- launcher ----------
extern "C" void kernel_launch(void* const* d_in, const int* in_sizes, int n_in,
                              void* d_out, int out_size, void* d_ws, size_t ws_size,
                              hipStream_t stream){
  const float* outputs       = (const float*)d_in[0];   // [8,256,512]
  const float* block_outputs = (const float*)d_in[1];   // [8,256,4,512]
  const float* W             = (const float*)d_in[2];   // [32000,512]

  u64* p1   = (u64*)((char*)d_ws + OFF_P1);
  u64* p2   = (u64*)((char*)d_ws + OFF_P2);
  u64* pE   = (u64*)((char*)d_ws + OFF_PE);
  int* flag = (int*)((char*)d_ws + OFF_FLAG);
  unsigned int* cnt  = (unsigned int*)((char*)d_ws + OFF_CNT);
  unsigned int* cnt2 = (unsigned int*)((char*)d_ws + OFF_CNT + 4);
  float* scores = (float*)((char*)d_ws + OFF_SCORES);

  init_kernel<<<MM / 256, 256, 0, stream>>>(p1, p2, pE, flag, cnt, cnt2);

  if (ws_size >= WS_NEED2){
    _Float16* Ahp = (_Float16*)((char*)d_ws + OFF_AH);
    _Float16* Alp = (_Float16*)((char*)d_ws + OFF_AL);
    _Float16* Whp = (_Float16*)((char*)d_ws + OFF_WH);
    _Float16* Wlp = (_Float16*)((char*)d_ws + OFF_WL);
    uint32_t* bmax  = (uint32_t*)((char*)d_ws + OFF_BMAX);
    uint32_t* pairs = (uint32_t*)((char*)d_ws + OFF_PAIRS);
    convert_kernel<<<(MM / 128) * 16, 256, 0, stream>>>(block_outputs, Ahp, Alp, 4096.0f);
    convert_kernel<<<(VV / 128) * 16, 256, 0, stream>>>(W, Whp, Wlp, 16384.0f);
    // pass 1: hi*hi approximate logits + top-2 per row + per-block top-1 keys
    gemm1_kernel<<<dim3(MM / BT, VV / BT), 512, 0, stream>>>(Ahp, Whp, p1, p2, bmax);
    // flag borderline rows + emit candidate (row, W-block) pairs (merged)
    resolve_cand_kernel<<<MM / 4, 256, 0, stream>>>(p1, p2, flag, bmax, pairs, cnt2);
    // exact fp32 rescore of candidate pairs only
    rescx_kernel<<<2048, 256, 0, stream>>>(Ahp, Alp, Whp, Wlp, pairs, cnt2, pE);
  } else if (ws_size >= WS_NEED1){
    _Float16* Ahp = (_Float16*)((char*)d_ws + OFF_AH);
    _Float16* Alp = (_Float16*)((char*)d_ws + OFF_AL);
    _Float16* Whp = (_Float16*)((char*)d_ws + OFF_WH);
    _Float16* Wlp = (_Float16*)((char*)d_ws + OFF_WL);
    convert_kernel<<<(MM / 128) * 16, 256, 0, stream>>>(block_outputs, Ahp, Alp, 4096.0f);
    convert_kernel<<<(VV / 128) * 16, 256, 0, stream>>>(W, Whp, Wlp, 16384.0f);
    gemm3_kernel<<<dim3(MM / TM, VV / TN), 256, 0, stream>>>(Ahp, Alp, Whp, Wlp, p1,
                                                             nullptr, nullptr);
  } else {
    gemm_fallback_kernel<<<dim3(GX, MM / TM), 256, 0, stream>>>(block_outputs, W, p1);
  }

  score_kernel<<<MM / 4, 256, 0, stream>>>(outputs, W, p1, pE, flag, scores);
  scan_kernel<<<1, 256, 0, stream>>>(scores, (float*)d_out);
}

// Round 9
// 505.300 us; speedup vs baseline: 11.8579x; 11.8579x over previous
//
#include <hip/hip_runtime.h>
#include <stdint.h>
#include <math.h>

// Problem dims (fixed by reference setup_inputs)
#define NN 8
#define TT 256
#define BB 4
#define DD 512
#define VV 32000
#define MM (NN*TT*BB)          // 8192 rows

// MFMA GEMM tiling (gemm3 full-path / fallback)
#define TM 128
#define TN 128
#define VT 5                   // n-tiles swept per block (fallback only now)
#define GX (VV/(TN*VT))        // 50
#define CHUNKS3 32             // 3-pass kernel: K=16 per chunk (2048 halves)

// gemm1 (pass-1) tiling: 256x256 tile, 8 waves, BK=32 ring-4 pipeline (R5/R7 best)
// NOTE (R8 lesson): acc = 128 regs/lane -> this shape is register-bound to
// 2 waves/SIMD (1 block/CU). Any launch_bounds >2 waves/EU forces scratch
// spill (R8: 30 GB HBM spill traffic, 18x slowdown). Do not raise occupancy
// on this kernel without shrinking the per-wave accumulator tile.
#define BT 256
#define NWB (VV/BT)            // 125 W-blocks of 256 cols

#define RCAP 2048              // max flagged rows
#define PCAP 16384             // max (row, W-block) rescore pairs
#define MARGIN 3.0e5f          // scaled-units confidence margin (~15 sigma)

typedef _Float16 half8  __attribute__((ext_vector_type(8)));
typedef float    f32x4  __attribute__((ext_vector_type(4)));
typedef float    f32x16 __attribute__((ext_vector_type(16)));
typedef unsigned long long u64;

#define MFMA32(a,b,c) __builtin_amdgcn_mfma_f32_32x32x16_f16((a),(b),(c),0,0,0)
#define MFMA16(a,b,c) __builtin_amdgcn_mfma_f32_16x16x32_f16((a),(b),(c),0,0,0)

// ---- workspace layout ----
#define OFF_P1     0ull              // 64KB u64[8192]
#define OFF_P2     65536ull          // 64KB
#define OFF_PE     131072ull         // 64KB
#define OFF_FLAG   196608ull         // 32KB int[8192]
#define OFF_LIST   229376ull         // 8KB  (unused, kept for layout stability)
#define OFF_CNT    237568ull         // 4KB region: cnt @ +0, cnt2 @ +4
#define OFF_SCORES 241664ull         // 32KB
#define OFF_AH     294912ull
#define AH_SZ      8388608ull        // 8192*512*2 B
#define OFF_AL     (OFF_AH + AH_SZ)
#define OFF_WH     (OFF_AL + AH_SZ)
#define WH_SZ      32768000ull       // 32000*512*2 B
#define OFF_WL     (OFF_WH + WH_SZ)
// candidate-pruning region
#define OFF_BMAX   (OFF_WL + WH_SZ)          // u32[125][8192] = 4,096,000 B
#define OFF_PAIRS  (OFF_BMAX + 4096000ull)   // u32[PCAP] = 65,536 B
#define WS_NEED2   (OFF_BMAX + 4194304ull)   // ~86.8 MB : full fast path
#define WS_NEED1   (OFF_WL + WH_SZ)          // ~82.6 MB : 3-pass-everywhere path

// ---------- helpers ----------

__device__ __forceinline__ uint32_t fkey(float v){
  uint32_t b = __float_as_uint(v);
  return b ^ ((b & 0x80000000u) ? 0xFFFFFFFFu : 0x80000000u);
}
__device__ __forceinline__ float unfkey(uint32_t k){
  uint32_t b = (k & 0x80000000u) ? (k ^ 0x80000000u) : ~k;
  return __uint_as_float(b);
}

__device__ __forceinline__ uint32_t rotl32(uint32_t x, int r){
  return (x << r) | (x >> (32 - r));
}
__device__ __forceinline__ void threefry2x32(uint32_t k0, uint32_t k1,
                                             uint32_t& x0, uint32_t& x1){
  const uint32_t ks0 = k0, ks1 = k1, ks2 = k0 ^ k1 ^ 0x1BD11BDAu;
  x0 += ks0; x1 += ks1;
  x0 += x1; x1 = rotl32(x1,13); x1 ^= x0;
  x0 += x1; x1 = rotl32(x1,15); x1 ^= x0;
  x0 += x1; x1 = rotl32(x1,26); x1 ^= x0;
  x0 += x1; x1 = rotl32(x1, 6); x1 ^= x0;
  x0 += ks1; x1 += ks2 + 1u;
  x0 += x1; x1 = rotl32(x1,17); x1 ^= x0;
  x0 += x1; x1 = rotl32(x1,29); x1 ^= x0;
  x0 += x1; x1 = rotl32(x1,16); x1 ^= x0;
  x0 += x1; x1 = rotl32(x1,24); x1 ^= x0;
  x0 += ks2; x1 += ks0 + 2u;
  x0 += x1; x1 = rotl32(x1,13); x1 ^= x0;
  x0 += x1; x1 = rotl32(x1,15); x1 ^= x0;
  x0 += x1; x1 = rotl32(x1,26); x1 ^= x0;
  x0 += x1; x1 = rotl32(x1, 6); x1 ^= x0;
  x0 += ks0; x1 += ks1 + 3u;
  x0 += x1; x1 = rotl32(x1,17); x1 ^= x0;
  x0 += x1; x1 = rotl32(x1,29); x1 ^= x0;
  x0 += x1; x1 = rotl32(x1,16); x1 ^= x0;
  x0 += x1; x1 = rotl32(x1,24); x1 ^= x0;
  x0 += ks1; x1 += ks2 + 4u;
  x0 += x1; x1 = rotl32(x1,13); x1 ^= x0;
  x0 += x1; x1 = rotl32(x1,15); x1 ^= x0;
  x0 += x1; x1 = rotl32(x1,26); x1 ^= x0;
  x0 += x1; x1 = rotl32(x1, 6); x1 ^= x0;
  x0 += ks2; x1 += ks0 + 5u;
}

__device__ __forceinline__ float uniform_from_bits(uint32_t bits){
  return __uint_as_float((bits >> 9) | 0x3f800000u) - 1.0f;
}

// async 16B global -> LDS (global addr per-lane, LDS dest wave-uniform + lane*16)
__device__ __forceinline__ void gload16(const _Float16* g, _Float16* l){
  __builtin_amdgcn_global_load_lds(
      (const __attribute__((address_space(1))) uint32_t*)g,
      (__attribute__((address_space(3))) uint32_t*)l, 16, 0, 0);
}

// ---------- kernel: init all header accumulators ----------
__global__ void init_kernel(u64* p1, u64* p2, u64* pE, int* flag,
                            unsigned int* cnt, unsigned int* cnt2){
  int i = blockIdx.x * blockDim.x + threadIdx.x;
  if (i < MM){ p1[i] = 0ULL; p2[i] = 0ULL; pE[i] = 0ULL; flag[i] = 0; }
  if (i == 0){ *cnt = 0u; *cnt2 = 0u; }
}

// ---------- conversion: fp32 [rows,512] -> split-f16 planes, tile layout ------
// hi = f16(x*scale), lo = f16(x*scale - hi) [natural residual].
// Plane chunk c = rt*8192 + kc*128 + rin (kc=k/8 in 0..63), 8 halves each.
__global__ __launch_bounds__(256)
void convert_kernel(const float* __restrict__ src,
                    _Float16* __restrict__ hi, _Float16* __restrict__ lo,
                    float scale){
  const int k0 = blockIdx.x & 15;       // 32-k slab
  const int rt = blockIdx.x >> 4;
  __shared__ _Float16 hbuf[4096], lbuf[4096];
  const int t = threadIdx.x;
  #pragma unroll
  for (int i = 0; i < 4; ++i){
    const int f = i * 256 + t;
    const int rin = f >> 3, c4 = f & 7;
    const float4 v4 = *(const float4*)&src[(size_t)(rt*128+rin)*DD + k0*32 + c4*4];
    const int base = (c4 >> 1) * 1024 + rin * 8 + (c4 & 1) * 4;
    float vv[4] = {v4.x, v4.y, v4.z, v4.w};
    #pragma unroll
    for (int j = 0; j < 4; ++j){
      const float s = vv[j] * scale;
      const _Float16 hh = (_Float16)s;
      hbuf[base + j] = hh;
      lbuf[base + j] = (_Float16)(s - (float)hh);
    }
  }
  __syncthreads();
  const size_t ob = ((size_t)rt * 8192 + (size_t)k0 * 512) * 8;
  #pragma unroll
  for (int i = 0; i < 2; ++i){
    const int cl = i * 256 + t;
    *(half8*)&hi[ob + (size_t)cl * 8] = *(const half8*)&hbuf[cl * 8];
    *(half8*)&lo[ob + (size_t)cl * 8] = *(const half8*)&lbuf[cl * 8];
  }
}

// ---------- kernel A: pass-1 hi*hi GEMM, 256x256 tile, ring-4 counted-vmcnt ---
// R7-verified structure (310 us, 868 TF). 8 waves (2 R-halves x 4 W-strips).
// BK=32 slabs, 3 slabs in flight, counted vmcnt, counted-lgkm two-cluster
// pipeline, setprio. Stores per-(row, 256-col W-block) approx top-1 key into
// bmax[bx][row] (coalesced) for candidate-block pruning of the rescore.
__global__ __launch_bounds__(512, 2)
void gemm1_kernel(const _Float16* __restrict__ Ahp, const _Float16* __restrict__ Whp,
                  u64* __restrict__ p1, u64* __restrict__ p2,
                  uint32_t* __restrict__ bmax){
  __shared__ __align__(16) _Float16 sR[4][8192];   // 64 KB: ring of 4 R K-slabs
  __shared__ __align__(16) _Float16 sW[4][8192];   // 64 KB: ring of 4 W K-slabs
  __shared__ u64 lmax1[BT];
  __shared__ uint32_t lmax2[BT];

  const int tid = threadIdx.x, wid = tid >> 6, lane = tid & 63;
  const int l31 = lane & 31, lhi = lane >> 5;
  const int wm = wid >> 2;          // 0..1 : which 128-row half of the R tile
  const int wn = wid & 3;           // 0..3 : which 64-col strip of the W tile
  const int by = blockIdx.x;        // R tile (32)
  const int bx = blockIdx.y;        // W tile (125)

  if (tid < BT){ lmax1[tid] = 0ULL; lmax2[tid] = 0u; }

  // staging geometry: 16 chunks of 512 halves per slot plane; wave stages 2 R + 2 W
  const int cc = wid * 2;                 // chunk pair base
  const int h  = cc >> 3;                 // which 128-row half-plane
  const size_t gsoff = (size_t)h * 65536 + (size_t)(cc & 7) * 512 + (size_t)lane * 8;
  const _Float16* grs = Ahp + (size_t)(by * 2) * 65536 + gsoff;
  const _Float16* gws = Whp + (size_t)(bx * 2) * 65536 + gsoff;
  const int lsoff = cc * 512;

  #define STAGE1(t) do { \
    const size_t ko_ = (size_t)(t) * 4096; \
    _Float16* lr_ = &sR[(t) & 3][lsoff]; \
    _Float16* lw_ = &sW[(t) & 3][lsoff]; \
    gload16(grs + ko_,       lr_); \
    gload16(grs + ko_ + 512, lr_ + 512); \
    gload16(gws + ko_,       lw_); \
    gload16(gws + ko_ + 512, lw_ + 512); \
  } while(0)

  STAGE1(0); STAGE1(1); STAGE1(2);   // 12 loads in flight

  f32x16 acc[2][4];
  #pragma unroll
  for (int c = 0; c < 2; ++c)
    #pragma unroll
    for (int m = 0; m < 4; ++m) acc[c][m] = (f32x16)0.0f;

  // fragment base offsets (in halves) within a slot: [half][kc 4][row 128][8]
  const int wbase = (wn >> 1) * 4096 + (wn & 1) * 512;  // + kc*1024 + c*256 + l31*8
  const int rbase = wm * 4096;                          // + kc*1024 + m*256 + l31*8

  for (int t = 0; t < 16; ++t){
    // counted vmcnt: retire own slab-t loads; keep up to 2 future slabs in flight
    if (t <= 13)      asm volatile("s_waitcnt vmcnt(8)" ::: "memory");
    else if (t == 14) asm volatile("s_waitcnt vmcnt(4)" ::: "memory");
    else              asm volatile("s_waitcnt vmcnt(0)" ::: "memory");
    __builtin_amdgcn_s_barrier();           // slab t fully in LDS (all waves)

    const _Float16* sRs = &sR[t & 3][0];
    const _Float16* sWs = &sW[t & 3][0];

    // ---- issue sub0 reads (kc = lhi): 6x ds_read_b128 ----
    half8 wf0[2], rf0[4];
    {
      const int kco = lhi * 1024;
      #pragma unroll
      for (int c = 0; c < 2; ++c)
        wf0[c] = *(const half8*)&sWs[wbase + kco + c * 256 + l31 * 8];
      #pragma unroll
      for (int m = 0; m < 4; ++m)
        rf0[m] = *(const half8*)&sRs[rbase + kco + m * 256 + l31 * 8];
    }
    __builtin_amdgcn_sched_barrier(0);      // sub0 reads issued before anything below

    // ---- issue sub1 reads (kc = 2+lhi) + next-slab stage (vmem) ----
    half8 wf1[2], rf1[4];
    {
      const int kco = (2 + lhi) * 1024;
      #pragma unroll
      for (int c = 0; c < 2; ++c)
        wf1[c] = *(const half8*)&sWs[wbase + kco + c * 256 + l31 * 8];
      #pragma unroll
      for (int m = 0; m < 4; ++m)
        rf1[m] = *(const half8*)&sRs[rbase + kco + m * 256 + l31 * 8];
    }
    if (t < 13) STAGE1(t + 3);              // writes slot (t-1)&3: all readers done

    // ---- cluster 0: wait sub0 only (sub1 + stage still in flight) ----
    asm volatile("s_waitcnt lgkmcnt(6)" ::: "memory");
    __builtin_amdgcn_sched_barrier(0);
    __builtin_amdgcn_s_setprio(1);
    #pragma unroll
    for (int c = 0; c < 2; ++c)
      #pragma unroll
      for (int m = 0; m < 4; ++m)
        acc[c][m] = MFMA32(wf0[c], rf0[m], acc[c][m]);
    __builtin_amdgcn_s_setprio(0);

    // ---- cluster 1: sub1 reads have been hiding under cluster 0 ----
    asm volatile("s_waitcnt lgkmcnt(0)" ::: "memory");
    __builtin_amdgcn_sched_barrier(0);
    __builtin_amdgcn_s_setprio(1);
    #pragma unroll
    for (int c = 0; c < 2; ++c)
      #pragma unroll
      for (int m = 0; m < 4; ++m)
        acc[c][m] = MFMA32(wf1[c], rf1[m], acc[c][m]);
    __builtin_amdgcn_s_setprio(0);
  }

  // ---- epilogue: per-lane running top-2 (rows are lane-local: D col = l31) ----
  // D row (v,lhi) -> W col = bx*256 + wn*64 + c*32 + (v&3)+8*(v>>2)+4*lhi
  // D col (l31)   -> R row = by*256 + wm*128 + m*32 + l31
  const int colbase = bx * BT + wn * 64;
  #pragma unroll
  for (int m = 0; m < 4; ++m){
    float t1 = -3.4e38f, t2 = -3.4e38f;
    uint32_t c1 = 0;
    #pragma unroll
    for (int c = 0; c < 2; ++c){
      #pragma unroll
      for (int v = 0; v < 16; ++v){
        const float val = acc[c][m][v];
        const uint32_t col = (uint32_t)(colbase + c * 32 + (v & 3) + 8 * (v >> 2) + 4 * lhi);
        const bool gt = val > t1;               // strict: earliest col wins ties
        t2 = gt ? t1 : fmaxf(t2, val);
        c1 = gt ? col : c1;
        t1 = fmaxf(t1, val);
      }
    }
    const u64 pk = ((u64)fkey(t1) << 32) | (u64)(~c1);
    const uint32_t k2 = fkey(t2);
    // merge the lane pair (lhi halves see disjoint cols of the same row)
    const u64 opk = __shfl_xor(pk, 32, 64);
    const uint32_t ok2 = __shfl_xor(k2, 32, 64);
    const u64 hi2 = pk > opk ? pk : opk;
    const uint32_t lo1 = (uint32_t)((pk > opk ? opk : pk) >> 32);
    uint32_t sec = k2 > ok2 ? k2 : ok2;
    sec = sec > lo1 ? sec : lo1;
    if (lhi == 0){
      const int row = wm * 128 + m * 32 + l31;
      const u64 old = atomicMax(&lmax1[row], hi2);
      const u64 losr = old < hi2 ? old : hi2;
      const uint32_t lk = (uint32_t)(losr >> 32);
      atomicMax(&lmax2[row], sec > lk ? sec : lk);
    }
  }

  __syncthreads();
  if (tid < BT){
    const int g = by * BT + tid;
    const u64 l1 = lmax1[tid];
    const u64 l2 = ((u64)lmax2[tid]) << 32;
    const u64 old = atomicMax(&p1[g], l1);
    const u64 losr = old < l1 ? old : l1;
    atomicMax(&p2[g], losr);
    atomicMax(&p2[g], l2);
    // per-(row, W-block) approx top-1 key; exclusive writer, coalesced
    bmax[(size_t)bx * MM + g] = (uint32_t)(l1 >> 32);
  }
  #undef STAGE1
}

// ---------- kernel: resolve borderline rows + emit (row, W-block) pairs ------
// Merged resolve+cand (one launch). Wave per row: gap test, flag write, then
// candidate-block scan: argmax of a flagged row lies in a block whose approx
// top-1 >= p1 - MARGIN (same error-bound logic as the gap test).
__global__ __launch_bounds__(256)
void resolve_cand_kernel(const u64* __restrict__ p1, const u64* __restrict__ p2,
                         int* __restrict__ flag,
                         const uint32_t* __restrict__ bmax,
                         uint32_t* __restrict__ pairs,
                         unsigned int* __restrict__ cnt2){
  const int wid = threadIdx.x >> 6, lane = threadIdx.x & 63;
  const int r = blockIdx.x * 4 + wid;
  const float f1 = unfkey((uint32_t)(p1[r] >> 32));
  const float f2 = unfkey((uint32_t)(p2[r] >> 32));
  if (f1 - f2 > MARGIN) return;
  if (lane == 0) flag[r] = 1;
  const float thr = f1 - MARGIN;
  #pragma unroll
  for (int s = 0; s < 2; ++s){
    const int b = lane + s * 64;
    if (b < NWB){
      const float f = unfkey(bmax[(size_t)b * MM + r]);
      if (f >= thr){
        const unsigned int i = atomicAdd(cnt2, 1u);
        if (i < PCAP) pairs[i] = ((uint32_t)r << 7) | (uint32_t)b;
      }
    }
  }
}

// ---------- kernel: exact fp32 rescore of candidate (row, block) pairs -------
// 256 threads per pair: thread t scores col b*256+t as sum_k (ah+al)(wh+wl)
// in fp32 (strictly more accurate than the old 3-pass MFMA rescore).
__global__ __launch_bounds__(256)
void rescx_kernel(const _Float16* __restrict__ Ahp, const _Float16* __restrict__ Alp,
                  const _Float16* __restrict__ Whp, const _Float16* __restrict__ Wlp,
                  const uint32_t* __restrict__ pairs,
                  const unsigned int* __restrict__ cnt2p,
                  u64* __restrict__ pE){
  __shared__ float as[DD];
  __shared__ u64 red;
  const unsigned int c2 = *cnt2p;
  const unsigned int n = c2 < (unsigned int)PCAP ? c2 : (unsigned int)PCAP;
  const int tid = threadIdx.x;

  for (unsigned int i = blockIdx.x; i < n; i += gridDim.x){
    const uint32_t pr = pairs[i];
    const int r = (int)(pr >> 7), b = (int)(pr & 127u);

    if (tid < 64){          // stage exact scaled A row: as[k] = ah + al
      const size_t base = ((size_t)(r >> 7) * 8192 + (size_t)tid * 128 + (r & 127)) * 8;
      const half8 h = *(const half8*)&Ahp[base];
      const half8 l = *(const half8*)&Alp[base];
      #pragma unroll
      for (int j = 0; j < 8; ++j) as[tid * 8 + j] = (float)h[j] + (float)l[j];
    }
    if (tid == 0) red = 0ULL;
    __syncthreads();

    const int v = b * 256 + tid;
    const size_t wb = ((size_t)(v >> 7) * 8192 + (size_t)(v & 127)) * 8;
    float s = 0.0f;
    for (int kc = 0; kc < 64; ++kc){
      const half8 wh = *(const half8*)&Whp[wb + (size_t)kc * 1024];
      const half8 wl = *(const half8*)&Wlp[wb + (size_t)kc * 1024];
      #pragma unroll
      for (int j = 0; j < 8; ++j)
        s = fmaf(as[kc * 8 + j], (float)wh[j] + (float)wl[j], s);
    }
    const u64 key = ((u64)fkey(s) << 32) | (u64)(~(uint32_t)v);
    atomicMax(&red, key);                    // LDS reduce
    __syncthreads();
    if (tid == 0) atomicMax(&pE[r], red);
    __syncthreads();
  }
}

// ---------- kernel B: 3-pass split-f16 GEMM + argmax (full-vocab path) -------
__global__ __launch_bounds__(256, 4)
void gemm3_kernel(const _Float16* __restrict__ Ahp, const _Float16* __restrict__ Alp,
                  const _Float16* __restrict__ Whp, const _Float16* __restrict__ Wlp,
                  u64* __restrict__ out,
                  const int* __restrict__ rowlist,
                  const unsigned int* __restrict__ cntp){
  if (cntp && (unsigned int)(blockIdx.x * TM) >= *cntp) return;

  __shared__ __align__(16) _Float16 sAh[2][2048], sAl[2][2048], sBh[2][2048], sBl[2][2048];
  __shared__ u64 lmax[TM];

  const int tid = threadIdx.x, wid = tid >> 6, lane = tid & 63;
  const int l31 = lane & 31, lhi = lane >> 5;
  const int wave_m = (wid & 1) * 64, wave_n = (wid >> 1) * 64;
  const int by = blockIdx.x;
  const int nt = blockIdx.y;

  if (tid < TM) lmax[tid] = 0ULL;

  _Float16* stg0 = (wid == 0) ? sAh[0] : (wid == 1) ? sAl[0] : (wid == 2) ? sBh[0] : sBl[0];
  _Float16* stg1 = (wid == 0) ? sAh[1] : (wid == 1) ? sAl[1] : (wid == 2) ? sBh[1] : sBl[1];

  f32x16 acc[2][2];
  #pragma unroll
  for (int i = 0; i < 2; ++i)
    #pragma unroll
    for (int j = 0; j < 2; ++j) acc[i][j] = (f32x16)0.0f;

  const _Float16* gbase =
      (wid == 0) ? Ahp + (size_t)by * 65536 : (wid == 1) ? Alp + (size_t)by * 65536
    : (wid == 2) ? Whp + (size_t)nt * 65536 :              Wlp + (size_t)nt * 65536;

  {
    const _Float16* g = gbase + lane * 8;
    #pragma unroll
    for (int j = 0; j < 4; ++j) gload16(g + j * 512, stg0 + j * 512);
  }

  for (int kk = 0; kk < CHUNKS3; ++kk){
    __syncthreads();
    if (kk < CHUNKS3 - 1){
      const _Float16* g = gbase + (size_t)(kk + 1) * 2048 + lane * 8;
      _Float16* s = (kk & 1) ? stg0 : stg1;
      #pragma unroll
      for (int j = 0; j < 4; ++j) gload16(g + j * 512, s + j * 512);
    }
    const int cb = kk & 1;

    half8 fah[2], fal[2], fbh[2], fbl[2];
    #pragma unroll
    for (int t = 0; t < 2; ++t){
      const int ra = lhi * 128 + wave_m + t * 32 + l31;
      const int rb = lhi * 128 + wave_n + t * 32 + l31;
      fah[t] = *(const half8*)&sAh[cb][ra * 8];
      fal[t] = *(const half8*)&sAl[cb][ra * 8];
      fbh[t] = *(const half8*)&sBh[cb][rb * 8];
      fbl[t] = *(const half8*)&sBl[cb][rb * 8];
    }
    #pragma unroll
    for (int ti = 0; ti < 2; ++ti)
      #pragma unroll
      for (int tj = 0; tj < 2; ++tj){
        acc[ti][tj] = MFMA32(fah[ti], fbh[tj], acc[ti][tj]);
        acc[ti][tj] = MFMA32(fah[ti], fbl[tj], acc[ti][tj]);
        acc[ti][tj] = MFMA32(fal[ti], fbh[tj], acc[ti][tj]);
      }
  }

  const int ncol0 = nt * TN + wave_n;
  #pragma unroll
  for (int ti = 0; ti < 2; ++ti){
    #pragma unroll
    for (int v = 0; v < 16; ++v){
      const int mloc = wave_m + ti * 32 + (v & 3) + 8 * (v >> 2) + 4 * lhi;
      u64 best = 0ULL;
      #pragma unroll
      for (int tj = 0; tj < 2; ++tj){
        const int col = ncol0 + tj * 32 + l31;
        const u64 p = ((u64)fkey(acc[ti][tj][v]) << 32) | (u64)(~(uint32_t)col);
        if (p > best) best = p;
      }
      #pragma unroll
      for (int m = 16; m > 0; m >>= 1){
        const u64 o = __shfl_xor(best, m, 64);
        if (o > best) best = o;
      }
      if (l31 == 0) atomicMax(&lmax[mloc], best);
    }
  }

  __syncthreads();
  if (tid < TM){
    int g;
    if (rowlist){
      const int i = by * TM + tid;
      const unsigned int c = *cntp;
      g = ((unsigned int)i < c) ? rowlist[i] : rowlist[0];
    } else {
      g = by * TM + tid;
    }
    atomicMax(&out[g], lmax[tid]);
  }
}

// ---------- fallback (round-3 verified): in-loop-convert GEMM ----------
__device__ __forceinline__ void cvt8(const float4& p, const float4& q, float scale,
                                     half8& h, half8& l){
  float v[8] = {p.x,p.y,p.z,p.w,q.x,q.y,q.z,q.w};
  #pragma unroll
  for (int j = 0; j < 8; ++j){
    const float s = v[j] * scale;
    const _Float16 hh = (_Float16)s;
    h[j] = hh;
    l[j] = (_Float16)((s - (float)hh) * 4096.0f);
  }
}

#define FBK 32
__global__ __launch_bounds__(256, 2)
void gemm_fallback_kernel(const float* __restrict__ A,
                          const float* __restrict__ W,
                          u64* __restrict__ packed){
  __shared__ __align__(16) _Float16 Ah[TM][40];
  __shared__ __align__(16) _Float16 Al[TM][40];
  __shared__ __align__(16) _Float16 Bh[TN][40];
  __shared__ __align__(16) _Float16 Bl[TN][40];
  __shared__ u64 lmax[TM];

  const int tid   = threadIdx.x;
  const int mtile = blockIdx.y * TM;
  const int wid    = tid >> 6;
  const int lane   = tid & 63;
  const int lm     = lane & 15;
  const int lk     = lane >> 4;
  const int wave_m = (wid & 1) * 64;
  const int wave_n = (wid >> 1) * 64;
  const int srow = tid >> 2;
  const int skc  = (tid & 3) * 8;

  if (tid < TM) lmax[tid] = 0ULL;

  for (int vt = 0; vt < VT; ++vt){
    const int ntile = (blockIdx.x * VT + vt) * TN;
    f32x4 acc1[4][4], acc2[4][4];
    #pragma unroll
    for (int i = 0; i < 4; ++i)
      #pragma unroll
      for (int j = 0; j < 4; ++j){ acc1[i][j] = (f32x4)0.0f; acc2[i][j] = (f32x4)0.0f; }

    for (int k0 = 0; k0 < DD; k0 += FBK){
      const float* pa0 = &A[(size_t)(mtile + srow     ) * DD + k0 + skc];
      const float* pa1 = &A[(size_t)(mtile + srow + 64) * DD + k0 + skc];
      const float* pb0 = &W[(size_t)(ntile + srow     ) * DD + k0 + skc];
      const float* pb1 = &W[(size_t)(ntile + srow + 64) * DD + k0 + skc];
      const float4 a00 = *(const float4*)(pa0), a01 = *(const float4*)(pa0 + 4);
      const float4 a10 = *(const float4*)(pa1), a11 = *(const float4*)(pa1 + 4);
      const float4 b00 = *(const float4*)(pb0), b01 = *(const float4*)(pb0 + 4);
      const float4 b10 = *(const float4*)(pb1), b11 = *(const float4*)(pb1 + 4);

      __syncthreads();
      half8 h, l;
      cvt8(a00, a01, 4096.0f,  h, l);
      *(half8*)&Ah[srow     ][skc] = h; *(half8*)&Al[srow     ][skc] = l;
      cvt8(a10, a11, 4096.0f,  h, l);
      *(half8*)&Ah[srow + 64][skc] = h; *(half8*)&Al[srow + 64][skc] = l;
      cvt8(b00, b01, 16384.0f, h, l);
      *(half8*)&Bh[srow     ][skc] = h; *(half8*)&Bl[srow     ][skc] = l;
      cvt8(b10, b11, 16384.0f, h, l);
      *(half8*)&Bh[srow + 64][skc] = h; *(half8*)&Bl[srow + 64][skc] = l;
      __syncthreads();

      half8 ah[4], al[4], bh[4], bl[4];
      #pragma unroll
      for (int ti = 0; ti < 4; ++ti){
        const int r = wave_m + ti * 16 + lm;
        ah[ti] = *(const half8*)&Ah[r][lk * 8];
        al[ti] = *(const half8*)&Al[r][lk * 8];
      }
      #pragma unroll
      for (int tj = 0; tj < 4; ++tj){
        const int r = wave_n + tj * 16 + lm;
        bh[tj] = *(const half8*)&Bh[r][lk * 8];
        bl[tj] = *(const half8*)&Bl[r][lk * 8];
      }
      #pragma unroll
      for (int ti = 0; ti < 4; ++ti)
        #pragma unroll
        for (int tj = 0; tj < 4; ++tj){
          acc1[ti][tj] = MFMA16(ah[ti], bh[tj], acc1[ti][tj]);
          acc2[ti][tj] = MFMA16(ah[ti], bl[tj], acc2[ti][tj]);
          acc2[ti][tj] = MFMA16(al[ti], bh[tj], acc2[ti][tj]);
        }
    }

    #pragma unroll
    for (int ti = 0; ti < 4; ++ti){
      #pragma unroll
      for (int v = 0; v < 4; ++v){
        const int mloc = wave_m + ti * 16 + lk * 4 + v;
        u64 best = 0ULL;
        #pragma unroll
        for (int tj = 0; tj < 4; ++tj){
          const int col = ntile + wave_n + tj * 16 + lm;
          const float lg = acc1[ti][tj][v] + acc2[ti][tj][v] * (1.0f/4096.0f);
          const u64 p = ((u64)fkey(lg) << 32) | (u64)(~(uint32_t)col);
          if (p > best) best = p;
        }
        atomicMax(&lmax[mloc], best);
      }
    }
  }

  __syncthreads();
  if (tid < TM) atomicMax(&packed[mtile + tid], lmax[tid]);
}

// ---------- kernel: scores[r] = sqrt(D) * dot(outputs[n,t,:], W[argmax_r]) ----
__global__ __launch_bounds__(256)
void score_kernel(const float* __restrict__ outputs,
                  const float* __restrict__ W,
                  const u64* __restrict__ p1, const u64* __restrict__ pE,
                  const int* __restrict__ flag,
                  float* __restrict__ scores){
  const int wave = threadIdx.x >> 6;
  const int lane = threadIdx.x & 63;
  const int r = blockIdx.x * 4 + wave;
  const u64 pe = pE[r];
  const u64 pk = (flag[r] && pe != 0ULL) ? pe : p1[r];
  const uint32_t idx = ~(uint32_t)pk;
  const int n = r >> 10;
  const int t = (r >> 2) & (TT - 1);
  const float* ov = outputs + ((size_t)(n * TT + t) << 9);
  const float* wv = W + (size_t)idx * DD;
  float s = 0.0f;
  #pragma unroll
  for (int j = 0; j < 8; ++j){
    const int d = lane + j * 64;
    s = fmaf(ov[d], wv[d], s);
  }
  #pragma unroll
  for (int off = 32; off > 0; off >>= 1) s += __shfl_down(s, off);
  if (lane == 0) scores[r] = s * 22.62741699796952f;  // float32(sqrt(512))
}

// ---------- kernel: sequential accept/reject scan + mask scatter ----------
__global__ __launch_bounds__(256)
void scan_kernel(const float* __restrict__ scores, float* __restrict__ mask_out){
  __shared__ float sc[MM];
  __shared__ float uu[TT * NN];

  const int tid = threadIdx.x;

  for (int i = tid; i < MM; i += 256){
    mask_out[i] = 0.0f;
    sc[i] = scores[i];
  }

  // Partitionable threefry (JAX >= 0.4.36): key' = tf2x32((0,42),(0,t));
  // element n: (o0,o1) = tf2x32(key',(0,n)); bits = o0^o1.
  {
    const int t = tid;
    uint32_t k0 = 0u, k1 = (uint32_t)t;
    threefry2x32(0u, 42u, k0, k1);
    #pragma unroll
    for (int n = 0; n < NN; ++n){
      uint32_t x0 = 0u, x1 = (uint32_t)n;
      threefry2x32(k0, k1, x0, x1);
      uu[t * NN + n] = uniform_from_bits(x0 ^ x1);
    }
  }
  __syncthreads();

  if (tid < NN){
    const int n = tid;
    int x = 0, y = 0;
    for (int t = 0; t < TT; ++t){
      const int idx0 = x * BB + y;
      mask_out[n * (TT * BB) + idx0] = 1.0f;
      const float scx0 = sc[n * (TT * BB) + idx0];
      const float scx1 = sc[n * (TT * BB) + t * BB];
      const float prob = 1.0f / (1.0f + expf(-((scx0 - scx1) / 10.0f)));
      int accept = (uu[t * NN + n] < prob) ? 1 : 0;
      if (y + accept >= BB) accept = 0;
      y = (y + accept) * accept;
      x = x * accept + (t + 1) * (1 - accept);
    }
  }
}

// ---------- launcher ----------
extern "C" void kernel_launch(void* const* d_in, const int* in_sizes, int n_in,
                              void* d_out, int out_size, void* d_ws, size_t ws_size,
                              hipStream_t stream){
  const float* outputs       = (const float*)d_in[0];   // [8,256,512]
  const float* block_outputs = (const float*)d_in[1];   // [8,256,4,512]
  const float* W             = (const float*)d_in[2];   // [32000,512]

  u64* p1   = (u64*)((char*)d_ws + OFF_P1);
  u64* p2   = (u64*)((char*)d_ws + OFF_P2);
  u64* pE   = (u64*)((char*)d_ws + OFF_PE);
  int* flag = (int*)((char*)d_ws + OFF_FLAG);
  unsigned int* cnt  = (unsigned int*)((char*)d_ws + OFF_CNT);
  unsigned int* cnt2 = (unsigned int*)((char*)d_ws + OFF_CNT + 4);
  float* scores = (float*)((char*)d_ws + OFF_SCORES);

  init_kernel<<<MM / 256, 256, 0, stream>>>(p1, p2, pE, flag, cnt, cnt2);

  if (ws_size >= WS_NEED2){
    _Float16* Ahp = (_Float16*)((char*)d_ws + OFF_AH);
    _Float16* Alp = (_Float16*)((char*)d_ws + OFF_AL);
    _Float16* Whp = (_Float16*)((char*)d_ws + OFF_WH);
    _Float16* Wlp = (_Float16*)((char*)d_ws + OFF_WL);
    uint32_t* bmax  = (uint32_t*)((char*)d_ws + OFF_BMAX);
    uint32_t* pairs = (uint32_t*)((char*)d_ws + OFF_PAIRS);
    convert_kernel<<<(MM / 128) * 16, 256, 0, stream>>>(block_outputs, Ahp, Alp, 4096.0f);
    convert_kernel<<<(VV / 128) * 16, 256, 0, stream>>>(W, Whp, Wlp, 16384.0f);
    // pass 1: hi*hi approximate logits + top-2 per row + per-block top-1 keys
    gemm1_kernel<<<dim3(MM / BT, VV / BT), 512, 0, stream>>>(Ahp, Whp, p1, p2, bmax);
    // flag borderline rows + emit candidate (row, W-block) pairs (merged)
    resolve_cand_kernel<<<MM / 4, 256, 0, stream>>>(p1, p2, flag, bmax, pairs, cnt2);
    // exact fp32 rescore of candidate pairs only
    rescx_kernel<<<2048, 256, 0, stream>>>(Ahp, Alp, Whp, Wlp, pairs, cnt2, pE);
  } else if (ws_size >= WS_NEED1){
    _Float16* Ahp = (_Float16*)((char*)d_ws + OFF_AH);
    _Float16* Alp = (_Float16*)((char*)d_ws + OFF_AL);
    _Float16* Whp = (_Float16*)((char*)d_ws + OFF_WH);
    _Float16* Wlp = (_Float16*)((char*)d_ws + OFF_WL);
    convert_kernel<<<(MM / 128) * 16, 256, 0, stream>>>(block_outputs, Ahp, Alp, 4096.0f);
    convert_kernel<<<(VV / 128) * 16, 256, 0, stream>>>(W, Whp, Wlp, 16384.0f);
    gemm3_kernel<<<dim3(MM / TM, VV / TN), 256, 0, stream>>>(Ahp, Alp, Whp, Wlp, p1,
                                                             nullptr, nullptr);
  } else {
    gemm_fallback_kernel<<<dim3(GX, MM / TM), 256, 0, stream>>>(block_outputs, W, p1);
  }

  score_kernel<<<MM / 4, 256, 0, stream>>>(outputs, W, p1, pE, flag, scores);
  scan_kernel<<<1, 256, 0, stream>>>(scores, (float*)d_out);
}